// Round 3
// baseline (1222.703 us; speedup 1.0000x reference)
//
#include <hip/hip_runtime.h>
#include <math.h>

#define S_LEN   8192
#define DMODEL  1024
#define B_SZ    2
#define NH      16
#define HD      64
#define KSEL    1024
#define CHUNKQ  256
#define WINDOW  512
#define NEG_BIG -1000000000.0f
#define RMSEPS  1.1920929e-07f

typedef short bf16x8 __attribute__((ext_vector_type(8)));
typedef float f32x4 __attribute__((ext_vector_type(4)));

// ---------------------------------------------------------------- zero output
__global__ void k_zero(float4* __restrict__ o, int n4) {
    int i = blockIdx.x * blockDim.x + threadIdx.x;
    if (i < n4) o[i] = make_float4(0.f, 0.f, 0.f, 0.f);
}

// ---------------------------------------------------------- routing scores
__global__ __launch_bounds__(256) void k_scores(const float* __restrict__ x,
                                                const float* __restrict__ cheby,
                                                float* __restrict__ scores) {
    int lin = blockIdx.x;
    int b = lin / (S_LEN - 1);
    int t = lin % (S_LEN - 1);
    const float4* xr = (const float4*)(x + ((size_t)b * S_LEN + t + 1) * DMODEL);
    const float4* cr = (const float4*)(cheby + ((size_t)b * S_LEN + t) * DMODEL);
    float4 xv = xr[threadIdx.x];
    float4 cv = cr[threadIdx.x];
    double acc = 0.0;
    {
        float vs[4] = {xv.x, xv.y, xv.z, xv.w};
        float cs[4] = {cv.x, cv.y, cv.z, cv.w};
#pragma unroll
        for (int j = 0; j < 4; ++j) {
            float ax = fmaxf(fabsf(vs[j]), 1e-7f);
            float ss = copysignf(1.0f - 1.0f / (1.0f + ax), vs[j]);
            acc += (double)fabsf(ss - cs[j]);
        }
    }
    int lane = threadIdx.x & 63, wid = threadIdx.x >> 6;
#pragma unroll
    for (int o = 32; o; o >>= 1) acc += __shfl_down(acc, o);
    __shared__ double wred[4];
    if (lane == 0) wred[wid] = acc;
    __syncthreads();
    if (threadIdx.x == 0) {
        double tot = wred[0] + wred[1] + wred[2] + wred[3];
        scores[(size_t)b * S_LEN + t] = (float)(tot * (1.0 / 1024.0));
    }
}

// ------------------------------------------------------------------- top-K
__global__ __launch_bounds__(1024) void k_topk(const float* __restrict__ scores,
                                               int* __restrict__ indices) {
    const int b = blockIdx.x;
    const int tid = threadIdx.x;
    const int lane = tid & 63, wid = tid >> 6;
    __shared__ unsigned vals[S_LEN];
    __shared__ unsigned hist[256];
    __shared__ unsigned sfx[256];
    __shared__ unsigned wsum[16];
    __shared__ unsigned bcast[2];
    __shared__ float fred[16];

    float mx = -1e30f;
    for (int i = tid; i < S_LEN - 1; i += 1024) {
        float v = scores[(size_t)b * S_LEN + i];
        vals[i] = __float_as_uint(v);
        mx = fmaxf(mx, v);
    }
#pragma unroll
    for (int o = 32; o; o >>= 1) mx = fmaxf(mx, __shfl_down(mx, o));
    if (lane == 0) fred[wid] = mx;
    __syncthreads();
    if (tid == 0) {
        float m2 = fred[0];
        for (int w = 1; w < 16; ++w) m2 = fmaxf(m2, fred[w]);
        vals[S_LEN - 1] = __float_as_uint(m2);
    }
    __syncthreads();

    unsigned prefix = 0, remaining = KSEL;
    for (int p = 3; p >= 0; --p) {
        unsigned hm = (p == 3) ? 0u : (0xFFFFFFFFu << ((p + 1) * 8));
        if (tid < 256) hist[tid] = 0u;
        __syncthreads();
        for (int i = tid; i < S_LEN; i += 1024) {
            unsigned v = vals[i];
            if ((v & hm) == (prefix & hm))
                atomicAdd(&hist[(v >> (p * 8)) & 255u], 1u);
        }
        __syncthreads();
        if (tid < 256) sfx[tid] = hist[tid];
        __syncthreads();
        for (int off = 1; off < 256; off <<= 1) {
            unsigned add = 0;
            if (tid < 256 && tid + off < 256) add = sfx[tid + off];
            __syncthreads();
            if (tid < 256) sfx[tid] += add;
            __syncthreads();
        }
        if (tid < 256) {
            unsigned Sb  = sfx[tid];
            unsigned Sb1 = (tid < 255) ? sfx[tid + 1] : 0u;
            if (Sb >= remaining && Sb1 < remaining) { bcast[0] = (unsigned)tid; bcast[1] = Sb1; }
        }
        __syncthreads();
        prefix |= bcast[0] << (p * 8);
        remaining -= bcast[1];
        __syncthreads();
    }
    const unsigned T = prefix;
    const unsigned need = remaining;

    const int p0 = tid * 8;
    unsigned vloc[8];
#pragma unroll
    for (int j = 0; j < 8; ++j) vloc[j] = vals[p0 + j];

    unsigned eqpre[8]; unsigned myeq = 0;
#pragma unroll
    for (int j = 0; j < 8; ++j) { eqpre[j] = myeq; myeq += (vloc[j] == T) ? 1u : 0u; }
    unsigned inc = myeq;
#pragma unroll
    for (int o = 1; o < 64; o <<= 1) { unsigned u = __shfl_up(inc, o); if (lane >= o) inc += u; }
    if (lane == 63) wsum[wid] = inc;
    __syncthreads();
    if (wid == 0) {
        unsigned w = (lane < 16) ? wsum[lane] : 0u;
        unsigned winc = w;
#pragma unroll
        for (int o = 1; o < 16; o <<= 1) { unsigned u = __shfl_up(winc, o); if (lane >= o) winc += u; }
        if (lane < 16) wsum[lane] = winc - w;
    }
    __syncthreads();
    const unsigned eqbase = wsum[wid] + inc - myeq;
    __syncthreads();

    unsigned fpre[8]; unsigned myf = 0; unsigned fl = 0;
#pragma unroll
    for (int j = 0; j < 8; ++j) {
        bool f = (vloc[j] > T) || ((vloc[j] == T) && (eqbase + eqpre[j] < need));
        fl |= (f ? 1u : 0u) << j;
        fpre[j] = myf;
        myf += f ? 1u : 0u;
    }
    unsigned inc2 = myf;
#pragma unroll
    for (int o = 1; o < 64; o <<= 1) { unsigned u = __shfl_up(inc2, o); if (lane >= o) inc2 += u; }
    if (lane == 63) wsum[wid] = inc2;
    __syncthreads();
    if (wid == 0) {
        unsigned w = (lane < 16) ? wsum[lane] : 0u;
        unsigned winc = w;
#pragma unroll
        for (int o = 1; o < 16; o <<= 1) { unsigned u = __shfl_up(winc, o); if (lane >= o) winc += u; }
        if (lane < 16) wsum[lane] = winc - w;
    }
    __syncthreads();
    const unsigned fbase = wsum[wid] + inc2 - myf;
#pragma unroll
    for (int j = 0; j < 8; ++j)
        if ((fl >> j) & 1u)
            indices[b * KSEL + fbase + fpre[j]] = p0 + j;
}

// ------------------------------------------------------------- RoPE tables
__global__ void k_rope_tab(const int* __restrict__ idxs,
                           float* __restrict__ rcos, float* __restrict__ rsin) {
    int g = blockIdx.x * blockDim.x + threadIdx.x;
    if (g >= B_SZ * KSEL * 32) return;
    int i = g & 31, bm = g >> 5;
    int b = bm >> 10, m = bm & 1023;
    float pos = (float)idxs[b * KSEL + m];
    double th = exp2(-(double)i * (13.287712379549449 / 32.0));
    float freq = pos * (float)th;
    float s, c;
    sincosf(freq, &s, &c);
    rcos[g] = c;
    rsin[g] = s;
}

__global__ __launch_bounds__(256) void k_rope_apply(float* __restrict__ qkv,
                                                    const float* __restrict__ rcos,
                                                    const float* __restrict__ rsin) {
    int bm = blockIdx.x;
    float* row = qkv + (size_t)bm * 4096;
    for (int p = threadIdx.x; p < 1536; p += 256) {
        int s = p / 512, r = p % 512;
        int h = r >> 5, i = r & 31;
        float c = rcos[bm * 32 + i], sn = rsin[bm * 32 + i];
        int off = s * 1024 + h * 64 + 2 * i;
        float x1 = row[off], x2 = row[off + 1];
        row[off]     = x1 * c - x2 * sn;
        row[off + 1] = x1 * sn + x2 * c;
    }
}

// -------------------------------------------- bf16 split helpers (hi/lo x3)
__device__ __forceinline__ unsigned pack_hi2(float a, float b) {
    return (__float_as_uint(a) >> 16) | (__float_as_uint(b) & 0xFFFF0000u);
}
__device__ __forceinline__ unsigned pack_lo2(float a, float b) {
    unsigned ua = __float_as_uint(a), ub = __float_as_uint(b);
    float ra = a - __uint_as_float(ua & 0xFFFF0000u);
    float rb = b - __uint_as_float(ub & 0xFFFF0000u);
    unsigned la = __float_as_uint(ra), lb = __float_as_uint(rb);
    la = la + 0x7FFFu + ((la >> 16) & 1u);
    lb = lb + 0x7FFFu + ((lb >> 16) & 1u);
    return (la >> 16) | (lb & 0xFFFF0000u);
}
__device__ __forceinline__ uint4 pack_hi8(float4 a, float4 b) {
    return make_uint4(pack_hi2(a.x, a.y), pack_hi2(a.z, a.w),
                      pack_hi2(b.x, b.y), pack_hi2(b.z, b.w));
}
__device__ __forceinline__ uint4 pack_lo8(float4 a, float4 b) {
    return make_uint4(pack_lo2(a.x, a.y), pack_lo2(a.z, a.w),
                      pack_lo2(b.x, b.y), pack_lo2(b.z, b.w));
}

#define PADK 56   // 112B row stride: 16B-aligned, 2-way-max bank pattern

// -------------------------------- QKV GEMM (gathered rows), MFMA bf16x3
// C[r, n] = sum_k x[row(r), k] * Wq[n, k]; 128x128 tile, BK=32, 4 waves 2x2.
__global__ __launch_bounds__(256) void k_qkv(const float* __restrict__ x,
                                             const float* __restrict__ Wq,
                                             const int* __restrict__ idxs,
                                             float* __restrict__ qkv) {
    __shared__ ushort As[2][128][PADK];
    __shared__ ushort Bs[2][128][PADK];
    __shared__ int rows[128];
    const int tid = threadIdx.x;
    const int bm = blockIdx.x, bn = blockIdx.y;
    if (tid < 128) {
        int r = bm * 128 + tid;
        int bb = r >> 10, mm = r & 1023;
        rows[tid] = bb * S_LEN + idxs[bb * KSEL + mm];
    }
    __syncthreads();
    const int srow = tid >> 1, koff = (tid & 1) * 16;
    const float* asrc = x + (size_t)rows[srow] * DMODEL + koff;
    const float* bsrc = Wq + (size_t)(bn * 128 + srow) * DMODEL + koff;
    const int wave = tid >> 6, lane = tid & 63;
    const int wm = wave >> 1, wn = wave & 1;
    const int fr = lane & 15, fk = (lane >> 4) * 8;
    f32x4 acc[4][4];
#pragma unroll
    for (int i = 0; i < 4; ++i)
#pragma unroll
        for (int j = 0; j < 4; ++j) acc[i][j] = (f32x4){0.f, 0.f, 0.f, 0.f};
    float4 a_ld[4], b_ld[4];
#pragma unroll
    for (int i = 0; i < 4; ++i) {
        a_ld[i] = *(const float4*)(asrc + i * 4);
        b_ld[i] = *(const float4*)(bsrc + i * 4);
    }
    for (int k0 = 0; k0 < DMODEL; k0 += 32) {
        __syncthreads();
        *(uint4*)&As[0][srow][koff]     = pack_hi8(a_ld[0], a_ld[1]);
        *(uint4*)&As[0][srow][koff + 8] = pack_hi8(a_ld[2], a_ld[3]);
        *(uint4*)&As[1][srow][koff]     = pack_lo8(a_ld[0], a_ld[1]);
        *(uint4*)&As[1][srow][koff + 8] = pack_lo8(a_ld[2], a_ld[3]);
        *(uint4*)&Bs[0][srow][koff]     = pack_hi8(b_ld[0], b_ld[1]);
        *(uint4*)&Bs[0][srow][koff + 8] = pack_hi8(b_ld[2], b_ld[3]);
        *(uint4*)&Bs[1][srow][koff]     = pack_lo8(b_ld[0], b_ld[1]);
        *(uint4*)&Bs[1][srow][koff + 8] = pack_lo8(b_ld[2], b_ld[3]);
        __syncthreads();
        if (k0 + 32 < DMODEL) {
#pragma unroll
            for (int i = 0; i < 4; ++i) {
                a_ld[i] = *(const float4*)(asrc + k0 + 32 + i * 4);
                b_ld[i] = *(const float4*)(bsrc + k0 + 32 + i * 4);
            }
        }
        bf16x8 ah[4], al[4], bh[4], bl[4];
#pragma unroll
        for (int i = 0; i < 4; ++i) {
            ah[i] = *(const bf16x8*)&As[0][wm * 64 + i * 16 + fr][fk];
            al[i] = *(const bf16x8*)&As[1][wm * 64 + i * 16 + fr][fk];
            bh[i] = *(const bf16x8*)&Bs[0][wn * 64 + i * 16 + fr][fk];
            bl[i] = *(const bf16x8*)&Bs[1][wn * 64 + i * 16 + fr][fk];
        }
#pragma unroll
        for (int mi = 0; mi < 4; ++mi)
#pragma unroll
            for (int ni = 0; ni < 4; ++ni) {
                acc[mi][ni] = __builtin_amdgcn_mfma_f32_16x16x32_bf16(ah[mi], bh[ni], acc[mi][ni], 0, 0, 0);
                acc[mi][ni] = __builtin_amdgcn_mfma_f32_16x16x32_bf16(ah[mi], bl[ni], acc[mi][ni], 0, 0, 0);
                acc[mi][ni] = __builtin_amdgcn_mfma_f32_16x16x32_bf16(al[mi], bh[ni], acc[mi][ni], 0, 0, 0);
            }
    }
    const int r0 = (lane >> 4) * 4;
#pragma unroll
    for (int mi = 0; mi < 4; ++mi)
#pragma unroll
        for (int ni = 0; ni < 4; ++ni) {
#pragma unroll
            for (int r = 0; r < 4; ++r) {
                int row = bm * 128 + wm * 64 + mi * 16 + r0 + r;
                int col = bn * 128 + wn * 64 + ni * 16 + fr;
                qkv[(size_t)row * 4096 + col] = acc[mi][ni][r];
            }
        }
}

// ------------------------------------------------------------- attention
// 4096 blocks x 64 threads (1 wave). Wave = 16 queries x 4 dim-quarters.
// K/V rows are wave-broadcast global loads (no LDS). Deferred-max softmax.
__global__ __launch_bounds__(64) void k_attn(const float* __restrict__ qkv,
                                             const int* __restrict__ idxs,
                                             float* __restrict__ o1,
                                             float* __restrict__ o2) {
    const int lin = blockIdx.x;
    const int qt = lin & 63;
    const int s  = (lin >> 6) & 1;
    const int h  = (lin >> 7) & 15;
    const int b  = lin >> 11;
    const int qbase = qt * 16;
    const int c = qt >> 4;
    const int k0 = (c >= 1) ? (c - 1) * 256 : 0;
    const int kend = qbase + 16;
    const int lane = threadIdx.x;
    const int qloc = lane >> 2, dp = lane & 3;

    const int* pidx = idxs + b * KSEL;
    const int pq = pidx[qbase + qloc];
    const float4* qp = (const float4*)(qkv + (size_t)(b * KSEL + qbase + qloc) * 4096
                                       + s * 1024 + h * 64 + dp * 16);
    float4 qv[4];
#pragma unroll
    for (int i = 0; i < 4; ++i) qv[i] = qp[i];
    float4 acc[4];
#pragma unroll
    for (int i = 0; i < 4; ++i) acc[i] = make_float4(0.f, 0.f, 0.f, 0.f);
    float m = -INFINITY, l = 0.f;

    const float* kbase = qkv + (size_t)b * KSEL * 4096 + 2048 + h * 64 + dp * 16;

#define AT_LOAD(KX, VX, PX, J) do {                                        \
        const float4* _p = (const float4*)(kbase + (size_t)(J) * 4096);    \
        KX[0] = _p[0]; KX[1] = _p[1]; KX[2] = _p[2]; KX[3] = _p[3];        \
        VX[0] = _p[256]; VX[1] = _p[257]; VX[2] = _p[258]; VX[3] = _p[259];\
        PX = pidx[J]; } while (0)

#define AT_STEP(KX, VX, PX) do {                                           \
        float t0 = qv[0].x*KX[0].x + qv[0].y*KX[0].y + qv[0].z*KX[0].z + qv[0].w*KX[0].w; \
        float t1 = qv[1].x*KX[1].x + qv[1].y*KX[1].y + qv[1].z*KX[1].z + qv[1].w*KX[1].w; \
        float t2 = qv[2].x*KX[2].x + qv[2].y*KX[2].y + qv[2].z*KX[2].z + qv[2].w*KX[2].w; \
        float t3 = qv[3].x*KX[3].x + qv[3].y*KX[3].y + qv[3].z*KX[3].z + qv[3].w*KX[3].w; \
        float part = (t0 + t1) + (t2 + t3);                                \
        part += __shfl_xor(part, 1);                                       \
        part += __shfl_xor(part, 2);                                       \
        float sc = part * 0.125f;                                          \
        sc = ((PX) <= pq && pq - (PX) < WINDOW) ? sc : NEG_BIG;            \
        if (__any(sc - m > 8.0f)) {                                        \
            float nm = fmaxf(m, sc);                                       \
            float sf = __expf(m - nm);                                     \
            l *= sf;                                                       \
            acc[0].x *= sf; acc[0].y *= sf; acc[0].z *= sf; acc[0].w *= sf;\
            acc[1].x *= sf; acc[1].y *= sf; acc[1].z *= sf; acc[1].w *= sf;\
            acc[2].x *= sf; acc[2].y *= sf; acc[2].z *= sf; acc[2].w *= sf;\
            acc[3].x *= sf; acc[3].y *= sf; acc[3].z *= sf; acc[3].w *= sf;\
            m = nm;                                                        \
        }                                                                  \
        float p = __expf(sc - m);                                          \
        l += p;                                                            \
        acc[0].x += p*VX[0].x; acc[0].y += p*VX[0].y; acc[0].z += p*VX[0].z; acc[0].w += p*VX[0].w; \
        acc[1].x += p*VX[1].x; acc[1].y += p*VX[1].y; acc[1].z += p*VX[1].z; acc[1].w += p*VX[1].w; \
        acc[2].x += p*VX[2].x; acc[2].y += p*VX[2].y; acc[2].z += p*VX[2].z; acc[2].w += p*VX[2].w; \
        acc[3].x += p*VX[3].x; acc[3].y += p*VX[3].y; acc[3].z += p*VX[3].z; acc[3].w += p*VX[3].w; \
    } while (0)

    float4 kA[4], vA[4], kB[4], vB[4];
    int pkA, pkB;
    AT_LOAD(kA, vA, pkA, k0);
    for (int j = k0; j < kend; j += 2) {
        AT_LOAD(kB, vB, pkB, j + 1);
        AT_STEP(kA, vA, pkA);
        int jn = (j + 2 < kend) ? (j + 2) : j;
        AT_LOAD(kA, vA, pkA, jn);
        AT_STEP(kB, vB, pkB);
    }
#undef AT_LOAD
#undef AT_STEP
    const float inv = 1.0f / l;
    float* dst = (s ? o2 : o1) + (size_t)(b * KSEL + qbase + qloc) * 1024 + h * 64 + dp * 16;
#pragma unroll
    for (int i = 0; i < 4; ++i)
        ((float4*)dst)[i] = make_float4(acc[i].x * inv, acc[i].y * inv,
                                        acc[i].z * inv, acc[i].w * inv);
}

// ---------------------- diff + output GEMM: y = (o1 - lam*o2) @ Wo^T, MFMA
// M=2048, N=1024, K=1024. 128x64 tile, BK=32, 4 waves 2x2 (wave: 64x32).
__global__ __launch_bounds__(256) void k_ogemm(const float* __restrict__ o1,
                                               const float* __restrict__ o2,
                                               const float* __restrict__ Wo,
                                               const float* __restrict__ dll,
                                               float* __restrict__ y) {
    __shared__ ushort As[2][128][PADK];
    __shared__ ushort Bs[2][64][PADK];
    __shared__ float lams[16];
    const int tid = threadIdx.x;
    const int bm = blockIdx.x, bn = blockIdx.y;
    if (tid < 16) lams[tid] = 1.0f / (1.0f + __expf(-dll[tid]));
    __syncthreads();
    const int srow = tid >> 1, koff = (tid & 1) * 16;
    const float* s1 = o1 + (size_t)(bm * 128 + srow) * 1024 + koff;
    const float* s2 = o2 + (size_t)(bm * 128 + srow) * 1024 + koff;
    const int browB = tid >> 2, koffB = (tid & 3) * 8;
    const float* bsrc = Wo + (size_t)(bn * 64 + browB) * 1024 + koffB;
    const int wave = tid >> 6, lane = tid & 63;
    const int wm = wave >> 1, wn = wave & 1;
    const int fr = lane & 15, fk = (lane >> 4) * 8;
    f32x4 acc[4][2];
#pragma unroll
    for (int i = 0; i < 4; ++i)
#pragma unroll
        for (int j = 0; j < 2; ++j) acc[i][j] = (f32x4){0.f, 0.f, 0.f, 0.f};
    float4 a1[4], a2[4], b_ld[2];
#pragma unroll
    for (int i = 0; i < 4; ++i) { a1[i] = *(const float4*)(s1 + i * 4); a2[i] = *(const float4*)(s2 + i * 4); }
    b_ld[0] = *(const float4*)(bsrc);
    b_ld[1] = *(const float4*)(bsrc + 4);
    for (int k0 = 0; k0 < 1024; k0 += 32) {
        float lam = lams[(k0 + koff) >> 6];
        float4 df[4];
#pragma unroll
        for (int i = 0; i < 4; ++i) {
            df[i].x = a1[i].x - lam * a2[i].x;
            df[i].y = a1[i].y - lam * a2[i].y;
            df[i].z = a1[i].z - lam * a2[i].z;
            df[i].w = a1[i].w - lam * a2[i].w;
        }
        __syncthreads();
        *(uint4*)&As[0][srow][koff]     = pack_hi8(df[0], df[1]);
        *(uint4*)&As[0][srow][koff + 8] = pack_hi8(df[2], df[3]);
        *(uint4*)&As[1][srow][koff]     = pack_lo8(df[0], df[1]);
        *(uint4*)&As[1][srow][koff + 8] = pack_lo8(df[2], df[3]);
        *(uint4*)&Bs[0][browB][koffB]   = pack_hi8(b_ld[0], b_ld[1]);
        *(uint4*)&Bs[1][browB][koffB]   = pack_lo8(b_ld[0], b_ld[1]);
        __syncthreads();
        if (k0 + 32 < 1024) {
#pragma unroll
            for (int i = 0; i < 4; ++i) {
                a1[i] = *(const float4*)(s1 + k0 + 32 + i * 4);
                a2[i] = *(const float4*)(s2 + k0 + 32 + i * 4);
            }
            b_ld[0] = *(const float4*)(bsrc + k0 + 32);
            b_ld[1] = *(const float4*)(bsrc + k0 + 36);
        }
        bf16x8 ah[4], al[4], bh[2], bl[2];
#pragma unroll
        for (int i = 0; i < 4; ++i) {
            ah[i] = *(const bf16x8*)&As[0][wm * 64 + i * 16 + fr][fk];
            al[i] = *(const bf16x8*)&As[1][wm * 64 + i * 16 + fr][fk];
        }
#pragma unroll
        for (int i = 0; i < 2; ++i) {
            bh[i] = *(const bf16x8*)&Bs[0][wn * 32 + i * 16 + fr][fk];
            bl[i] = *(const bf16x8*)&Bs[1][wn * 32 + i * 16 + fr][fk];
        }
#pragma unroll
        for (int mi = 0; mi < 4; ++mi)
#pragma unroll
            for (int ni = 0; ni < 2; ++ni) {
                acc[mi][ni] = __builtin_amdgcn_mfma_f32_16x16x32_bf16(ah[mi], bh[ni], acc[mi][ni], 0, 0, 0);
                acc[mi][ni] = __builtin_amdgcn_mfma_f32_16x16x32_bf16(ah[mi], bl[ni], acc[mi][ni], 0, 0, 0);
                acc[mi][ni] = __builtin_amdgcn_mfma_f32_16x16x32_bf16(al[mi], bh[ni], acc[mi][ni], 0, 0, 0);
            }
    }
    const int r0 = (lane >> 4) * 4;
#pragma unroll
    for (int mi = 0; mi < 4; ++mi)
#pragma unroll
        for (int ni = 0; ni < 2; ++ni) {
#pragma unroll
            for (int r = 0; r < 4; ++r) {
                int row = bm * 128 + wm * 64 + mi * 16 + r0 + r;
                int col = bn * 64 + wn * 32 + ni * 16 + fr;
                y[(size_t)row * 1024 + col] = acc[mi][ni][r];
            }
        }
}

// -------------------------------------------------- RMS norm + scatter rows
__global__ __launch_bounds__(256) void k_rms(const float* __restrict__ y,
                                             const int* __restrict__ idxs,
                                             const float* __restrict__ w,
                                             float* __restrict__ out) {
    const int r = blockIdx.x;
    const int b = r >> 10, m = r & 1023;
    const float4 v = ((const float4*)(y + (size_t)r * 1024))[threadIdx.x];
    double ss = (double)v.x * v.x + (double)v.y * v.y + (double)v.z * v.z + (double)v.w * v.w;
    int lane = threadIdx.x & 63, wid = threadIdx.x >> 6;
#pragma unroll
    for (int o = 32; o; o >>= 1) ss += __shfl_down(ss, o);
    __shared__ double wr[4];
    if (lane == 0) wr[wid] = ss;
    __syncthreads();
    double tot = wr[0] + wr[1] + wr[2] + wr[3];
    float sc = 1.0f / sqrtf((float)(tot * (1.0 / 1024.0)) + RMSEPS);
    float4 wv = ((const float4*)w)[threadIdx.x];
    int row = idxs[b * KSEL + m];
    float4 o4 = make_float4((v.x * sc) * wv.x, (v.y * sc) * wv.y,
                            (v.z * sc) * wv.z, (v.w * sc) * wv.w);
    ((float4*)(out + ((size_t)b * S_LEN + row) * 1024))[threadIdx.x] = o4;
}

// ----------------------------------------------------------------- launcher
extern "C" void kernel_launch(void* const* d_in, const int* in_sizes, int n_in,
                              void* d_out, int out_size, void* d_ws, size_t ws_size,
                              hipStream_t stream) {
    (void)in_sizes; (void)n_in; (void)out_size; (void)ws_size;
    const float* x     = (const float*)d_in[0];
    const float* cheby = (const float*)d_in[1];
    const float* Wqkv  = (const float*)d_in[2];
    const float* Wo    = (const float*)d_in[3];
    const float* rmsw  = (const float*)d_in[4];
    const float* dll   = (const float*)d_in[5];
    float* out = (float*)d_out;

    float* ws = (float*)d_ws;
    float* scores = ws;                                   // 16384
    int*   indices = (int*)(ws + 16384);                  // 2048 ints
    float* rcos = ws + 16384 + 2048;                      // 65536
    float* rsin = rcos + 65536;                           // 65536
    float* qkv  = rsin + 65536;                           // 8388608 (B*K*4096)
    float* o1   = qkv + 8388608;                          // 2097152
    float* o2   = o1 + 2097152;                           // 2097152
    float* yb   = o2 + 2097152;                           // 2097152

    k_zero<<<16384, 256, 0, stream>>>((float4*)out, (B_SZ * S_LEN * DMODEL) / 4);
    k_scores<<<B_SZ * (S_LEN - 1), 256, 0, stream>>>(x, cheby, scores);
    k_topk<<<B_SZ, 1024, 0, stream>>>(scores, indices);
    k_rope_tab<<<(B_SZ * KSEL * 32 + 255) / 256, 256, 0, stream>>>(indices, rcos, rsin);
    k_qkv<<<dim3(16, 32), 256, 0, stream>>>(x, Wqkv, indices, qkv);
    k_rope_apply<<<B_SZ * KSEL, 256, 0, stream>>>(qkv, rcos, rsin);
    k_attn<<<4096, 64, 0, stream>>>(qkv, indices, o1, o2);
    k_ogemm<<<dim3(16, 16), 256, 0, stream>>>(o1, o2, Wo, dll, yb);
    k_rms<<<B_SZ * KSEL, 256, 0, stream>>>(yb, indices, rmsw, out);
}

// Round 4
// 393.455 us; speedup vs baseline: 3.1076x; 3.1076x over previous
//
#include <hip/hip_runtime.h>
#include <math.h>

#define S_LEN   8192
#define DMODEL  1024
#define B_SZ    2
#define NH      16
#define HD      64
#define KSEL    1024
#define CHUNKQ  256
#define WINDOW  512
#define NEG_BIG -1000000000.0f
#define RMSEPS  1.1920929e-07f

typedef short bf16x8 __attribute__((ext_vector_type(8)));
typedef float f32x4 __attribute__((ext_vector_type(4)));

// ---------------------------------------------------------------- zero output
__global__ void k_zero(float4* __restrict__ o, int n4) {
    int i = blockIdx.x * blockDim.x + threadIdx.x;
    if (i < n4) o[i] = make_float4(0.f, 0.f, 0.f, 0.f);
}

// ---------------------------------------------------------- routing scores
__global__ __launch_bounds__(256) void k_scores(const float* __restrict__ x,
                                                const float* __restrict__ cheby,
                                                float* __restrict__ scores) {
    int lin = blockIdx.x;
    int b = lin / (S_LEN - 1);
    int t = lin % (S_LEN - 1);
    const float4* xr = (const float4*)(x + ((size_t)b * S_LEN + t + 1) * DMODEL);
    const float4* cr = (const float4*)(cheby + ((size_t)b * S_LEN + t) * DMODEL);
    float4 xv = xr[threadIdx.x];
    float4 cv = cr[threadIdx.x];
    double acc = 0.0;
    {
        float vs[4] = {xv.x, xv.y, xv.z, xv.w};
        float cs[4] = {cv.x, cv.y, cv.z, cv.w};
#pragma unroll
        for (int j = 0; j < 4; ++j) {
            float ax = fmaxf(fabsf(vs[j]), 1e-7f);
            float ss = copysignf(1.0f - 1.0f / (1.0f + ax), vs[j]);
            acc += (double)fabsf(ss - cs[j]);
        }
    }
    int lane = threadIdx.x & 63, wid = threadIdx.x >> 6;
#pragma unroll
    for (int o = 32; o; o >>= 1) acc += __shfl_down(acc, o);
    __shared__ double wred[4];
    if (lane == 0) wred[wid] = acc;
    __syncthreads();
    if (threadIdx.x == 0) {
        double tot = wred[0] + wred[1] + wred[2] + wred[3];
        scores[(size_t)b * S_LEN + t] = (float)(tot * (1.0 / 1024.0));
    }
}

// ------------------------------------------------------------------- top-K
__global__ __launch_bounds__(1024) void k_topk(const float* __restrict__ scores,
                                               int* __restrict__ indices) {
    const int b = blockIdx.x;
    const int tid = threadIdx.x;
    const int lane = tid & 63, wid = tid >> 6;
    __shared__ unsigned vals[S_LEN];
    __shared__ unsigned hist[256];
    __shared__ unsigned sfx[256];
    __shared__ unsigned wsum[16];
    __shared__ unsigned bcast[2];
    __shared__ float fred[16];

    float mx = -1e30f;
    for (int i = tid; i < S_LEN - 1; i += 1024) {
        float v = scores[(size_t)b * S_LEN + i];
        vals[i] = __float_as_uint(v);
        mx = fmaxf(mx, v);
    }
#pragma unroll
    for (int o = 32; o; o >>= 1) mx = fmaxf(mx, __shfl_down(mx, o));
    if (lane == 0) fred[wid] = mx;
    __syncthreads();
    if (tid == 0) {
        float m2 = fred[0];
        for (int w = 1; w < 16; ++w) m2 = fmaxf(m2, fred[w]);
        vals[S_LEN - 1] = __float_as_uint(m2);
    }
    __syncthreads();

    unsigned prefix = 0, remaining = KSEL;
    for (int p = 3; p >= 0; --p) {
        unsigned hm = (p == 3) ? 0u : (0xFFFFFFFFu << ((p + 1) * 8));
        if (tid < 256) hist[tid] = 0u;
        __syncthreads();
        for (int i = tid; i < S_LEN; i += 1024) {
            unsigned v = vals[i];
            if ((v & hm) == (prefix & hm))
                atomicAdd(&hist[(v >> (p * 8)) & 255u], 1u);
        }
        __syncthreads();
        if (tid < 256) sfx[tid] = hist[tid];
        __syncthreads();
        for (int off = 1; off < 256; off <<= 1) {
            unsigned add = 0;
            if (tid < 256 && tid + off < 256) add = sfx[tid + off];
            __syncthreads();
            if (tid < 256) sfx[tid] += add;
            __syncthreads();
        }
        if (tid < 256) {
            unsigned Sb  = sfx[tid];
            unsigned Sb1 = (tid < 255) ? sfx[tid + 1] : 0u;
            if (Sb >= remaining && Sb1 < remaining) { bcast[0] = (unsigned)tid; bcast[1] = Sb1; }
        }
        __syncthreads();
        prefix |= bcast[0] << (p * 8);
        remaining -= bcast[1];
        __syncthreads();
    }
    const unsigned T = prefix;
    const unsigned need = remaining;

    const int p0 = tid * 8;
    unsigned vloc[8];
#pragma unroll
    for (int j = 0; j < 8; ++j) vloc[j] = vals[p0 + j];

    unsigned eqpre[8]; unsigned myeq = 0;
#pragma unroll
    for (int j = 0; j < 8; ++j) { eqpre[j] = myeq; myeq += (vloc[j] == T) ? 1u : 0u; }
    unsigned inc = myeq;
#pragma unroll
    for (int o = 1; o < 64; o <<= 1) { unsigned u = __shfl_up(inc, o); if (lane >= o) inc += u; }
    if (lane == 63) wsum[wid] = inc;
    __syncthreads();
    if (wid == 0) {
        unsigned w = (lane < 16) ? wsum[lane] : 0u;
        unsigned winc = w;
#pragma unroll
        for (int o = 1; o < 16; o <<= 1) { unsigned u = __shfl_up(winc, o); if (lane >= o) winc += u; }
        if (lane < 16) wsum[lane] = winc - w;
    }
    __syncthreads();
    const unsigned eqbase = wsum[wid] + inc - myeq;
    __syncthreads();

    unsigned fpre[8]; unsigned myf = 0; unsigned fl = 0;
#pragma unroll
    for (int j = 0; j < 8; ++j) {
        bool f = (vloc[j] > T) || ((vloc[j] == T) && (eqbase + eqpre[j] < need));
        fl |= (f ? 1u : 0u) << j;
        fpre[j] = myf;
        myf += f ? 1u : 0u;
    }
    unsigned inc2 = myf;
#pragma unroll
    for (int o = 1; o < 64; o <<= 1) { unsigned u = __shfl_up(inc2, o); if (lane >= o) inc2 += u; }
    if (lane == 63) wsum[wid] = inc2;
    __syncthreads();
    if (wid == 0) {
        unsigned w = (lane < 16) ? wsum[lane] : 0u;
        unsigned winc = w;
#pragma unroll
        for (int o = 1; o < 16; o <<= 1) { unsigned u = __shfl_up(winc, o); if (lane >= o) winc += u; }
        if (lane < 16) wsum[lane] = winc - w;
    }
    __syncthreads();
    const unsigned fbase = wsum[wid] + inc2 - myf;
#pragma unroll
    for (int j = 0; j < 8; ++j)
        if ((fl >> j) & 1u)
            indices[b * KSEL + fbase + fpre[j]] = p0 + j;
}

// ------------------------------------------------------------- RoPE tables
__global__ void k_rope_tab(const int* __restrict__ idxs,
                           float* __restrict__ rcos, float* __restrict__ rsin) {
    int g = blockIdx.x * blockDim.x + threadIdx.x;
    if (g >= B_SZ * KSEL * 32) return;
    int i = g & 31, bm = g >> 5;
    int b = bm >> 10, m = bm & 1023;
    float pos = (float)idxs[b * KSEL + m];
    double th = exp2(-(double)i * (13.287712379549449 / 32.0));
    float freq = pos * (float)th;
    float s, c;
    sincosf(freq, &s, &c);
    rcos[g] = c;
    rsin[g] = s;
}

__global__ __launch_bounds__(256) void k_rope_apply(float* __restrict__ qkv,
                                                    const float* __restrict__ rcos,
                                                    const float* __restrict__ rsin) {
    int bm = blockIdx.x;
    float* row = qkv + (size_t)bm * 4096;
    for (int p = threadIdx.x; p < 1536; p += 256) {
        int s = p / 512, r = p % 512;
        int h = r >> 5, i = r & 31;
        float c = rcos[bm * 32 + i], sn = rsin[bm * 32 + i];
        int off = s * 1024 + h * 64 + 2 * i;
        float x1 = row[off], x2 = row[off + 1];
        row[off]     = x1 * c - x2 * sn;
        row[off + 1] = x1 * sn + x2 * c;
    }
}

// -------------------------------------------- bf16 split helpers (hi/lo x3)
__device__ __forceinline__ unsigned pack_hi2(float a, float b) {
    return (__float_as_uint(a) >> 16) | (__float_as_uint(b) & 0xFFFF0000u);
}
__device__ __forceinline__ unsigned pack_lo2(float a, float b) {
    unsigned ua = __float_as_uint(a), ub = __float_as_uint(b);
    float ra = a - __uint_as_float(ua & 0xFFFF0000u);
    float rb = b - __uint_as_float(ub & 0xFFFF0000u);
    unsigned la = __float_as_uint(ra), lb = __float_as_uint(rb);
    la = la + 0x7FFFu + ((la >> 16) & 1u);
    lb = lb + 0x7FFFu + ((lb >> 16) & 1u);
    return (la >> 16) | (lb & 0xFFFF0000u);
}
__device__ __forceinline__ uint4 pack_hi8(float4 a, float4 b) {
    return make_uint4(pack_hi2(a.x, a.y), pack_hi2(a.z, a.w),
                      pack_hi2(b.x, b.y), pack_hi2(b.z, b.w));
}
__device__ __forceinline__ uint4 pack_lo8(float4 a, float4 b) {
    return make_uint4(pack_lo2(a.x, a.y), pack_lo2(a.z, a.w),
                      pack_lo2(b.x, b.y), pack_lo2(b.z, b.w));
}

#define PADK 56   // 112B row stride: 16B-aligned, 2-way-max bank pattern

// -------------------------------- QKV GEMM (gathered rows), MFMA bf16x3
__global__ __launch_bounds__(256) void k_qkv(const float* __restrict__ x,
                                             const float* __restrict__ Wq,
                                             const int* __restrict__ idxs,
                                             float* __restrict__ qkv) {
    __shared__ ushort As[2][128][PADK];
    __shared__ ushort Bs[2][128][PADK];
    __shared__ int rows[128];
    const int tid = threadIdx.x;
    const int bm = blockIdx.x, bn = blockIdx.y;
    if (tid < 128) {
        int r = bm * 128 + tid;
        int bb = r >> 10, mm = r & 1023;
        rows[tid] = bb * S_LEN + idxs[bb * KSEL + mm];
    }
    __syncthreads();
    const int srow = tid >> 1, koff = (tid & 1) * 16;
    const float* asrc = x + (size_t)rows[srow] * DMODEL + koff;
    const float* bsrc = Wq + (size_t)(bn * 128 + srow) * DMODEL + koff;
    const int wave = tid >> 6, lane = tid & 63;
    const int wm = wave >> 1, wn = wave & 1;
    const int fr = lane & 15, fk = (lane >> 4) * 8;
    f32x4 acc[4][4];
#pragma unroll
    for (int i = 0; i < 4; ++i)
#pragma unroll
        for (int j = 0; j < 4; ++j) acc[i][j] = (f32x4){0.f, 0.f, 0.f, 0.f};
    float4 a_ld[4], b_ld[4];
#pragma unroll
    for (int i = 0; i < 4; ++i) {
        a_ld[i] = *(const float4*)(asrc + i * 4);
        b_ld[i] = *(const float4*)(bsrc + i * 4);
    }
    for (int k0 = 0; k0 < DMODEL; k0 += 32) {
        __syncthreads();
        *(uint4*)&As[0][srow][koff]     = pack_hi8(a_ld[0], a_ld[1]);
        *(uint4*)&As[0][srow][koff + 8] = pack_hi8(a_ld[2], a_ld[3]);
        *(uint4*)&As[1][srow][koff]     = pack_lo8(a_ld[0], a_ld[1]);
        *(uint4*)&As[1][srow][koff + 8] = pack_lo8(a_ld[2], a_ld[3]);
        *(uint4*)&Bs[0][srow][koff]     = pack_hi8(b_ld[0], b_ld[1]);
        *(uint4*)&Bs[0][srow][koff + 8] = pack_hi8(b_ld[2], b_ld[3]);
        *(uint4*)&Bs[1][srow][koff]     = pack_lo8(b_ld[0], b_ld[1]);
        *(uint4*)&Bs[1][srow][koff + 8] = pack_lo8(b_ld[2], b_ld[3]);
        __syncthreads();
        if (k0 + 32 < DMODEL) {
#pragma unroll
            for (int i = 0; i < 4; ++i) {
                a_ld[i] = *(const float4*)(asrc + k0 + 32 + i * 4);
                b_ld[i] = *(const float4*)(bsrc + k0 + 32 + i * 4);
            }
        }
        bf16x8 ah[4], al[4], bh[4], bl[4];
#pragma unroll
        for (int i = 0; i < 4; ++i) {
            ah[i] = *(const bf16x8*)&As[0][wm * 64 + i * 16 + fr][fk];
            al[i] = *(const bf16x8*)&As[1][wm * 64 + i * 16 + fr][fk];
            bh[i] = *(const bf16x8*)&Bs[0][wn * 64 + i * 16 + fr][fk];
            bl[i] = *(const bf16x8*)&Bs[1][wn * 64 + i * 16 + fr][fk];
        }
#pragma unroll
        for (int mi = 0; mi < 4; ++mi)
#pragma unroll
            for (int ni = 0; ni < 4; ++ni) {
                acc[mi][ni] = __builtin_amdgcn_mfma_f32_16x16x32_bf16(ah[mi], bh[ni], acc[mi][ni], 0, 0, 0);
                acc[mi][ni] = __builtin_amdgcn_mfma_f32_16x16x32_bf16(ah[mi], bl[ni], acc[mi][ni], 0, 0, 0);
                acc[mi][ni] = __builtin_amdgcn_mfma_f32_16x16x32_bf16(al[mi], bh[ni], acc[mi][ni], 0, 0, 0);
            }
    }
    const int r0 = (lane >> 4) * 4;
#pragma unroll
    for (int mi = 0; mi < 4; ++mi)
#pragma unroll
        for (int ni = 0; ni < 4; ++ni) {
#pragma unroll
            for (int r = 0; r < 4; ++r) {
                int row = bm * 128 + wm * 64 + mi * 16 + r0 + r;
                int col = bn * 128 + wn * 64 + ni * 16 + fr;
                qkv[(size_t)row * 4096 + col] = acc[mi][ni][r];
            }
        }
}

// ------------------------------------------------------------- attention
// grid: 512 = b(2) x h(16) x qblock(16 of 64 queries); 256 threads = 4 waves.
// Wave = 16 queries x 4 dim-quarters, BOTH streams per lane (shared K/V reads).
// Sorted indices => mask is contiguous range [jlo, qg]; waves skip tiles
// entirely below their min(jlo). Deferred-max online softmax (THR=8).
__global__ __launch_bounds__(256) void k_attn(const float* __restrict__ qkv,
                                              const int* __restrict__ idxs,
                                              float* __restrict__ o1,
                                              float* __restrict__ o2) {
    const int lin = blockIdx.x;
    const int qb = lin & 15;
    const int h  = (lin >> 4) & 15;
    const int b  = lin >> 8;
    const int tid = threadIdx.x;
    const int wave = tid >> 6, lane = tid & 63;
    const int qloc = lane >> 2, dp = lane & 3;
    const int qg = qb * 64 + wave * 16 + qloc;
    const int c = qg >> 8;
    const int cstart = (c >= 1) ? (c - 1) * 256 : 0;

    __shared__ float Kt[64][68];
    __shared__ float Vt[64][68];
    __shared__ int wred[4];

    const int* pidx = idxs + b * KSEL;
    const int pq = pidx[qg];
    // jlo = smallest j in [cstart, qg] with pidx[j] > pq - WINDOW
    int blo_ = cstart, bhi_ = qg;
    const int target = pq - WINDOW;
    while (blo_ < bhi_) {
        int mid = (blo_ + bhi_) >> 1;
        if (pidx[mid] > target) bhi_ = mid; else blo_ = mid + 1;
    }
    const int jlo = blo_;

    // wave min(jlo) for tile skipping; block min for stage range
    int wlo = jlo;
#pragma unroll
    for (int o = 32; o; o >>= 1) wlo = min(wlo, __shfl_xor(wlo, o));
    if (lane == 0) wred[wave] = wlo;
    __syncthreads();
    const int blo = min(min(wred[0], wred[1]), min(wred[2], wred[3]));
    const int t0 = blo >> 6;
    const int t1 = qb;   // tiles t0..qb, tile t covers sel keys [64t, 64t+64)

    const float* qrow = qkv + (size_t)(b * KSEL + qg) * 4096 + h * 64 + dp * 16;
    float4 q1v[4], q2v[4];
#pragma unroll
    for (int i = 0; i < 4; ++i) {
        q1v[i] = ((const float4*)qrow)[i];
        q2v[i] = ((const float4*)(qrow + 1024))[i];
    }
    float4 a1[4], a2[4];
#pragma unroll
    for (int i = 0; i < 4; ++i) {
        a1[i] = make_float4(0.f, 0.f, 0.f, 0.f);
        a2[i] = make_float4(0.f, 0.f, 0.f, 0.f);
    }
    float m1 = NEG_BIG, l1 = 0.f, m2 = NEG_BIG, l2 = 0.f;

    const float* kvsrc = qkv + (size_t)b * KSEL * 4096 + 2048 + h * 64;

    for (int t = t0; t <= t1; ++t) {
        __syncthreads();
        {
            const int kk = tid >> 2, cc = (tid & 3) * 16;
            const float* src = kvsrc + (size_t)(t * 64 + kk) * 4096 + cc;
#pragma unroll
            for (int i = 0; i < 4; ++i) {
                *(float4*)&Kt[kk][cc + 4 * i] = *(const float4*)(src + 4 * i);
                *(float4*)&Vt[kk][cc + 4 * i] = *(const float4*)(src + 1024 + 4 * i);
            }
        }
        __syncthreads();
        if (t * 64 + 63 >= wlo) {   // wave-uniform: skip fully-masked tiles
#pragma unroll 4
            for (int j = 0; j < 64; ++j) {
                const int jg = t * 64 + j;
                const float* kr = &Kt[j][dp * 16];
                float4 k0 = *(const float4*)&kr[0];
                float4 k1 = *(const float4*)&kr[4];
                float4 k2 = *(const float4*)&kr[8];
                float4 k3 = *(const float4*)&kr[12];
                float p1a = q1v[0].x*k0.x + q1v[0].y*k0.y + q1v[0].z*k0.z + q1v[0].w*k0.w
                          + q1v[1].x*k1.x + q1v[1].y*k1.y + q1v[1].z*k1.z + q1v[1].w*k1.w
                          + q1v[2].x*k2.x + q1v[2].y*k2.y + q1v[2].z*k2.z + q1v[2].w*k2.w
                          + q1v[3].x*k3.x + q1v[3].y*k3.y + q1v[3].z*k3.z + q1v[3].w*k3.w;
                float p2a = q2v[0].x*k0.x + q2v[0].y*k0.y + q2v[0].z*k0.z + q2v[0].w*k0.w
                          + q2v[1].x*k1.x + q2v[1].y*k1.y + q2v[1].z*k1.z + q2v[1].w*k1.w
                          + q2v[2].x*k2.x + q2v[2].y*k2.y + q2v[2].z*k2.z + q2v[2].w*k2.w
                          + q2v[3].x*k3.x + q2v[3].y*k3.y + q2v[3].z*k3.z + q2v[3].w*k3.w;
                p1a += __shfl_xor(p1a, 1); p1a += __shfl_xor(p1a, 2);
                p2a += __shfl_xor(p2a, 1); p2a += __shfl_xor(p2a, 2);
                const bool ok = (jg >= jlo) && (jg <= qg);
                float sc1 = ok ? p1a * 0.125f : NEG_BIG;
                float sc2 = ok ? p2a * 0.125f : NEG_BIG;
                float d1 = sc1 - m1, d2 = sc2 - m2;
                if (__any(fmaxf(d1, d2) > 8.0f)) {
                    float nm1 = fmaxf(m1, sc1), nm2 = fmaxf(m2, sc2);
                    float sf1 = __expf(m1 - nm1), sf2 = __expf(m2 - nm2);
                    l1 *= sf1; l2 *= sf2;
#pragma unroll
                    for (int i = 0; i < 4; ++i) {
                        a1[i].x *= sf1; a1[i].y *= sf1; a1[i].z *= sf1; a1[i].w *= sf1;
                        a2[i].x *= sf2; a2[i].y *= sf2; a2[i].z *= sf2; a2[i].w *= sf2;
                    }
                    m1 = nm1; m2 = nm2;
                    d1 = sc1 - m1; d2 = sc2 - m2;
                }
                float p1 = __expf(d1), p2 = __expf(d2);
                l1 += p1; l2 += p2;
                const float* vr = &Vt[j][dp * 16];
                float4 v0 = *(const float4*)&vr[0];
                float4 v1 = *(const float4*)&vr[4];
                float4 v2 = *(const float4*)&vr[8];
                float4 v3 = *(const float4*)&vr[12];
                a1[0].x += p1*v0.x; a1[0].y += p1*v0.y; a1[0].z += p1*v0.z; a1[0].w += p1*v0.w;
                a1[1].x += p1*v1.x; a1[1].y += p1*v1.y; a1[1].z += p1*v1.z; a1[1].w += p1*v1.w;
                a1[2].x += p1*v2.x; a1[2].y += p1*v2.y; a1[2].z += p1*v2.z; a1[2].w += p1*v2.w;
                a1[3].x += p1*v3.x; a1[3].y += p1*v3.y; a1[3].z += p1*v3.z; a1[3].w += p1*v3.w;
                a2[0].x += p2*v0.x; a2[0].y += p2*v0.y; a2[0].z += p2*v0.z; a2[0].w += p2*v0.w;
                a2[1].x += p2*v1.x; a2[1].y += p2*v1.y; a2[1].z += p2*v1.z; a2[1].w += p2*v1.w;
                a2[2].x += p2*v2.x; a2[2].y += p2*v2.y; a2[2].z += p2*v2.z; a2[2].w += p2*v2.w;
                a2[3].x += p2*v3.x; a2[3].y += p2*v3.y; a2[3].z += p2*v3.z; a2[3].w += p2*v3.w;
            }
        }
    }
    const float i1 = 1.0f / l1, i2 = 1.0f / l2;
    const size_t obase = (size_t)(b * KSEL + qg) * 1024 + h * 64 + dp * 16;
    float* d1p = o1 + obase;
    float* d2p = o2 + obase;
#pragma unroll
    for (int i = 0; i < 4; ++i) {
        ((float4*)d1p)[i] = make_float4(a1[i].x * i1, a1[i].y * i1, a1[i].z * i1, a1[i].w * i1);
        ((float4*)d2p)[i] = make_float4(a2[i].x * i2, a2[i].y * i2, a2[i].z * i2, a2[i].w * i2);
    }
}

// ---------------------- diff + output GEMM: y = (o1 - lam*o2) @ Wo^T, MFMA
__global__ __launch_bounds__(256) void k_ogemm(const float* __restrict__ o1,
                                               const float* __restrict__ o2,
                                               const float* __restrict__ Wo,
                                               const float* __restrict__ dll,
                                               float* __restrict__ y) {
    __shared__ ushort As[2][128][PADK];
    __shared__ ushort Bs[2][64][PADK];
    __shared__ float lams[16];
    const int tid = threadIdx.x;
    const int bm = blockIdx.x, bn = blockIdx.y;
    if (tid < 16) lams[tid] = 1.0f / (1.0f + __expf(-dll[tid]));
    __syncthreads();
    const int srow = tid >> 1, koff = (tid & 1) * 16;
    const float* s1 = o1 + (size_t)(bm * 128 + srow) * 1024 + koff;
    const float* s2 = o2 + (size_t)(bm * 128 + srow) * 1024 + koff;
    const int browB = tid >> 2, koffB = (tid & 3) * 8;
    const float* bsrc = Wo + (size_t)(bn * 64 + browB) * 1024 + koffB;
    const int wave = tid >> 6, lane = tid & 63;
    const int wm = wave >> 1, wn = wave & 1;
    const int fr = lane & 15, fk = (lane >> 4) * 8;
    f32x4 acc[4][2];
#pragma unroll
    for (int i = 0; i < 4; ++i)
#pragma unroll
        for (int j = 0; j < 2; ++j) acc[i][j] = (f32x4){0.f, 0.f, 0.f, 0.f};
    float4 a1[4], a2[4], b_ld[2];
#pragma unroll
    for (int i = 0; i < 4; ++i) { a1[i] = *(const float4*)(s1 + i * 4); a2[i] = *(const float4*)(s2 + i * 4); }
    b_ld[0] = *(const float4*)(bsrc);
    b_ld[1] = *(const float4*)(bsrc + 4);
    for (int k0 = 0; k0 < 1024; k0 += 32) {
        float lam = lams[(k0 + koff) >> 6];
        float4 df[4];
#pragma unroll
        for (int i = 0; i < 4; ++i) {
            df[i].x = a1[i].x - lam * a2[i].x;
            df[i].y = a1[i].y - lam * a2[i].y;
            df[i].z = a1[i].z - lam * a2[i].z;
            df[i].w = a1[i].w - lam * a2[i].w;
        }
        __syncthreads();
        *(uint4*)&As[0][srow][koff]     = pack_hi8(df[0], df[1]);
        *(uint4*)&As[0][srow][koff + 8] = pack_hi8(df[2], df[3]);
        *(uint4*)&As[1][srow][koff]     = pack_lo8(df[0], df[1]);
        *(uint4*)&As[1][srow][koff + 8] = pack_lo8(df[2], df[3]);
        *(uint4*)&Bs[0][browB][koffB]   = pack_hi8(b_ld[0], b_ld[1]);
        *(uint4*)&Bs[1][browB][koffB]   = pack_lo8(b_ld[0], b_ld[1]);
        __syncthreads();
        if (k0 + 32 < 1024) {
#pragma unroll
            for (int i = 0; i < 4; ++i) {
                a1[i] = *(const float4*)(s1 + k0 + 32 + i * 4);
                a2[i] = *(const float4*)(s2 + k0 + 32 + i * 4);
            }
            b_ld[0] = *(const float4*)(bsrc + k0 + 32);
            b_ld[1] = *(const float4*)(bsrc + k0 + 36);
        }
        bf16x8 ah[4], al[4], bh[2], bl[2];
#pragma unroll
        for (int i = 0; i < 4; ++i) {
            ah[i] = *(const bf16x8*)&As[0][wm * 64 + i * 16 + fr][fk];
            al[i] = *(const bf16x8*)&As[1][wm * 64 + i * 16 + fr][fk];
        }
#pragma unroll
        for (int i = 0; i < 2; ++i) {
            bh[i] = *(const bf16x8*)&Bs[0][wn * 32 + i * 16 + fr][fk];
            bl[i] = *(const bf16x8*)&Bs[1][wn * 32 + i * 16 + fr][fk];
        }
#pragma unroll
        for (int mi = 0; mi < 4; ++mi)
#pragma unroll
            for (int ni = 0; ni < 2; ++ni) {
                acc[mi][ni] = __builtin_amdgcn_mfma_f32_16x16x32_bf16(ah[mi], bh[ni], acc[mi][ni], 0, 0, 0);
                acc[mi][ni] = __builtin_amdgcn_mfma_f32_16x16x32_bf16(ah[mi], bl[ni], acc[mi][ni], 0, 0, 0);
                acc[mi][ni] = __builtin_amdgcn_mfma_f32_16x16x32_bf16(al[mi], bh[ni], acc[mi][ni], 0, 0, 0);
            }
    }
    const int r0 = (lane >> 4) * 4;
#pragma unroll
    for (int mi = 0; mi < 4; ++mi)
#pragma unroll
        for (int ni = 0; ni < 2; ++ni) {
#pragma unroll
            for (int r = 0; r < 4; ++r) {
                int row = bm * 128 + wm * 64 + mi * 16 + r0 + r;
                int col = bn * 64 + wn * 32 + ni * 16 + fr;
                y[(size_t)row * 1024 + col] = acc[mi][ni][r];
            }
        }
}

// -------------------------------------------------- RMS norm + scatter rows
__global__ __launch_bounds__(256) void k_rms(const float* __restrict__ y,
                                             const int* __restrict__ idxs,
                                             const float* __restrict__ w,
                                             float* __restrict__ out) {
    const int r = blockIdx.x;
    const int b = r >> 10, m = r & 1023;
    const float4 v = ((const float4*)(y + (size_t)r * 1024))[threadIdx.x];
    double ss = (double)v.x * v.x + (double)v.y * v.y + (double)v.z * v.z + (double)v.w * v.w;
    int lane = threadIdx.x & 63, wid = threadIdx.x >> 6;
#pragma unroll
    for (int o = 32; o; o >>= 1) ss += __shfl_down(ss, o);
    __shared__ double wr[4];
    if (lane == 0) wr[wid] = ss;
    __syncthreads();
    double tot = wr[0] + wr[1] + wr[2] + wr[3];
    float sc = 1.0f / sqrtf((float)(tot * (1.0 / 1024.0)) + RMSEPS);
    float4 wv = ((const float4*)w)[threadIdx.x];
    int row = idxs[b * KSEL + m];
    float4 o4 = make_float4((v.x * sc) * wv.x, (v.y * sc) * wv.y,
                            (v.z * sc) * wv.z, (v.w * sc) * wv.w);
    ((float4*)(out + ((size_t)b * S_LEN + row) * 1024))[threadIdx.x] = o4;
}

// ----------------------------------------------------------------- launcher
extern "C" void kernel_launch(void* const* d_in, const int* in_sizes, int n_in,
                              void* d_out, int out_size, void* d_ws, size_t ws_size,
                              hipStream_t stream) {
    (void)in_sizes; (void)n_in; (void)out_size; (void)ws_size;
    const float* x     = (const float*)d_in[0];
    const float* cheby = (const float*)d_in[1];
    const float* Wqkv  = (const float*)d_in[2];
    const float* Wo    = (const float*)d_in[3];
    const float* rmsw  = (const float*)d_in[4];
    const float* dll   = (const float*)d_in[5];
    float* out = (float*)d_out;

    float* ws = (float*)d_ws;
    float* scores = ws;                                   // 16384
    int*   indices = (int*)(ws + 16384);                  // 2048 ints
    float* rcos = ws + 16384 + 2048;                      // 65536
    float* rsin = rcos + 65536;                           // 65536
    float* qkv  = rsin + 65536;                           // 8388608 (B*K*4096)
    float* o1   = qkv + 8388608;                          // 2097152
    float* o2   = o1 + 2097152;                           // 2097152
    float* yb   = o2 + 2097152;                           // 2097152

    k_zero<<<16384, 256, 0, stream>>>((float4*)out, (B_SZ * S_LEN * DMODEL) / 4);
    k_scores<<<B_SZ * (S_LEN - 1), 256, 0, stream>>>(x, cheby, scores);
    k_topk<<<B_SZ, 1024, 0, stream>>>(scores, indices);
    k_rope_tab<<<(B_SZ * KSEL * 32 + 255) / 256, 256, 0, stream>>>(indices, rcos, rsin);
    k_qkv<<<dim3(16, 32), 256, 0, stream>>>(x, Wqkv, indices, qkv);
    k_rope_apply<<<B_SZ * KSEL, 256, 0, stream>>>(qkv, rcos, rsin);
    k_attn<<<512, 256, 0, stream>>>(qkv, indices, o1, o2);
    k_ogemm<<<dim3(16, 16), 256, 0, stream>>>(o1, o2, Wo, dll, yb);
    k_rms<<<B_SZ * KSEL, 256, 0, stream>>>(yb, indices, rmsw, out);
}